// Round 1
// baseline (418.992 us; speedup 1.0000x reference)
//
#include <hip/hip_runtime.h>
#include <hip/hip_fp16.h>
#include <math.h>

#define IN_DIM 128
#define HID 32
#define HEADS 12
#define FDIM (HEADS*HID)   // 384
#define SLOPE 0.2f

typedef __attribute__((ext_vector_type(8))) short short8;
typedef __attribute__((ext_vector_type(4))) float float4v;
typedef __attribute__((ext_vector_type(4))) float f32x4;
typedef _Float16 hv2 __attribute__((ext_vector_type(2)));

__device__ __forceinline__ float dot2acc(hv2 a, hv2 b, float c) {
#if __has_builtin(__builtin_amdgcn_fdot2)
    return __builtin_amdgcn_fdot2(a, b, c, false);
#else
    return c + (float)a.x * (float)b.x + (float)a.y * (float)b.y;
#endif
}

// async global->LDS 16B per lane; LDS dst is wave-uniform base + lane*16
__device__ __forceinline__ void async_cp16(const void* g, void* l) {
    __builtin_amdgcn_global_load_lds(
        (const __attribute__((address_space(1))) void*)g,
        (__attribute__((address_space(3))) void*)l, 16, 0, 0);
}

// ---------------- CSR build ----------------

__global__ void hist_kernel(const int* __restrict__ dst, int* __restrict__ cnt, int E) {
    int e = blockIdx.x * blockDim.x + threadIdx.x;
    if (e < E) atomicAdd(&cnt[dst[e]], 1);
}

__global__ __launch_bounds__(256) void scan_partial_kernel(const int* __restrict__ cnt,
                                                           int* __restrict__ partials, int n) {
    int i = blockIdx.x * 256 + threadIdx.x;
    int v = (i < n) ? cnt[i] : 0;
#pragma unroll
    for (int off = 1; off < 64; off <<= 1) v += __shfl_xor(v, off);
    __shared__ int sh[4];
    if ((threadIdx.x & 63) == 0) sh[threadIdx.x >> 6] = v;
    __syncthreads();
    if (threadIdx.x == 0) partials[blockIdx.x] = sh[0] + sh[1] + sh[2] + sh[3];
}

__global__ __launch_bounds__(1024) void scan_top_kernel(int* __restrict__ partials, int nb) {
    __shared__ int sh[1024];
    int t = threadIdx.x;
    int v = (t < nb) ? partials[t] : 0;
    sh[t] = v;
    __syncthreads();
    for (int off = 1; off < 1024; off <<= 1) {
        int u = (t >= off) ? sh[t - off] : 0;
        __syncthreads();
        sh[t] += u;
        __syncthreads();
    }
    if (t < nb) partials[t] = sh[t] - v;   // exclusive
}

__global__ __launch_bounds__(256) void scan_final_kernel(const int* __restrict__ cnt,
                                                         const int* __restrict__ partials,
                                                         int* __restrict__ start,
                                                         int* __restrict__ cursor, int n) {
    __shared__ int sh[256];
    int t = threadIdx.x;
    int i = blockIdx.x * 256 + t;
    int v = (i < n) ? cnt[i] : 0;
    sh[t] = v;
    __syncthreads();
    for (int off = 1; off < 256; off <<= 1) {
        int u = (t >= off) ? sh[t - off] : 0;
        __syncthreads();
        sh[t] += u;
        __syncthreads();
    }
    int ex = sh[t] - v + partials[blockIdx.x];
    if (i < n) {
        start[i] = ex;
        cursor[i] = ex;
        if (i == n - 1) start[n] = ex + v;
    }
}

__global__ void scatter_kernel(const int* __restrict__ src, const int* __restrict__ dst,
                               int* __restrict__ cursor, int* __restrict__ srcs,
                               int* __restrict__ srcsOff, int E) {
    int e = blockIdx.x * blockDim.x + threadIdx.x;
    if (e < E) {
        int d = dst[e];
        int pos = atomicAdd(&cursor[d], 1);
        int s = src[e];
        srcs[pos] = s;
        srcsOff[pos] = s * (FDIM * 2);   // byte offset into f16 feature rows
    }
}

// ---------------- bf16 split helpers ----------------

__device__ __forceinline__ unsigned int bf16_rne(float f) {
    unsigned int u = __float_as_uint(f);
    return (u + 0x7FFFu + ((u >> 16) & 1u)) >> 16;
}

// ---------------- merged prep: weights (both layers) + att f16 ----------------

__global__ void prep_all(const float* __restrict__ Wl0, const float* __restrict__ Wr0,
                         const float* __restrict__ Wl1, const float* __restrict__ Wr1,
                         const float* __restrict__ a0, const float* __restrict__ a1,
                         short* __restrict__ Bl0h, short* __restrict__ Bl0l,
                         short* __restrict__ Br0h, short* __restrict__ Br0l,
                         short* __restrict__ Bl1h, short* __restrict__ Bl1l,
                         short* __restrict__ Br1h, short* __restrict__ Br1l,
                         _Float16* __restrict__ attH) {
    int idx = blockIdx.x * 256 + threadIdx.x;
    if (idx < 49152) {
        int k = idx / 384, n = idx - k * 384;
        float w1 = Wl0[idx], w2 = Wr0[idx];
        unsigned int h1 = bf16_rne(w1);
        unsigned int l1 = bf16_rne(w1 - __uint_as_float(h1 << 16));
        unsigned int h2 = bf16_rne(w2);
        unsigned int l2 = bf16_rne(w2 - __uint_as_float(h2 << 16));
        Bl0h[n * 128 + k] = (short)h1;  Bl0l[n * 128 + k] = (short)l1;
        Br0h[n * 128 + k] = (short)h2;  Br0l[n * 128 + k] = (short)l2;
    } else if (idx < 61440) {
        int i2 = idx - 49152;
        int k = i2 / 384, n = i2 - k * 384;
        float w1 = Wl1[i2], w2 = Wr1[i2];
        unsigned int h1 = bf16_rne(w1);
        unsigned int l1 = bf16_rne(w1 - __uint_as_float(h1 << 16));
        unsigned int h2 = bf16_rne(w2);
        unsigned int l2 = bf16_rne(w2 - __uint_as_float(h2 << 16));
        Bl1h[n * 32 + k] = (short)h1;  Bl1l[n * 32 + k] = (short)l1;
        Br1h[n * 32 + k] = (short)h2;  Br1l[n * 32 + k] = (short)l2;
    } else if (idx < 62208) {
        int i2 = idx - 61440;
        attH[i2] = (_Float16)((i2 < 384) ? a0[i2] : a1[i2 - 384]);
    }
}

// ---------------- input prep: x fp32 -> bf16 hi/lo planes (float4 vectorized) ----------------

__global__ void conv_x_kernel(const float* __restrict__ A, short* __restrict__ Ah,
                              short* __restrict__ Al, int total4) {
    int i = blockIdx.x * 256 + threadIdx.x;
    if (i >= total4) return;
    float4 v = ((const float4*)A)[i];
    float fs[4] = {v.x, v.y, v.z, v.w};
    unsigned int hb[4], lb[4];
#pragma unroll
    for (int t = 0; t < 4; t++) {
        hb[t] = bf16_rne(fs[t]);
        lb[t] = bf16_rne(fs[t] - __uint_as_float(hb[t] << 16));
    }
    uint2 hp, lp;
    hp.x = hb[0] | (hb[1] << 16); hp.y = hb[2] | (hb[3] << 16);
    lp.x = lb[0] | (lb[1] << 16); lp.y = lb[2] | (lb[3] << 16);
    ((uint2*)Ah)[i] = hp;
    ((uint2*)Al)[i] = lp;
}

// ---------------- bf16x3 MFMA GEMM pair, async global->LDS staging ----------------
// (unchanged from previous round)

__global__ __launch_bounds__(256) void gemm_pair_async(
    const short* __restrict__ Ahi, const short* __restrict__ Alo,
    const short* __restrict__ B1h, const short* __restrict__ B1l,
    const float* __restrict__ bias1, __half* __restrict__ C1,
    const short* __restrict__ B2h, const short* __restrict__ B2l,
    const float* __restrict__ bias2, __half* __restrict__ C2,
    int M, int K) {
    __shared__ __align__(16) unsigned char smem[33792];
    int tid = threadIdx.x;
    int lane = tid & 63;
    int wave = tid >> 6;
    int wm = wave & 1, wn = wave >> 1;
    int rowBase = blockIdx.x * 128;
    bool second = blockIdx.y >= 3;
    int colBase = (blockIdx.y - (second ? 3 : 0)) * 128;
    const short* Bh  = second ? B2h : B1h;
    const short* Bl  = second ? B2l : B1l;
    const float* bias = second ? bias2 : bias1;
    __half*      C    = second ? C2 : C1;

    const short8* AsHi = (const short8*)smem;
    const short8* AsLo = (const short8*)(smem + 8192);
    const short8* BsHi = (const short8*)(smem + 16384);
    const short8* BsLo = (const short8*)(smem + 24576);

    const short* gsrc[8];
    void* ldst[8];
#pragma unroll
    for (int q = 0; q < 8; q++) {
        int t  = (q & 1) * 4 + wave;          // fragment tile 0..7
        int rc = t * 16 + (lane & 15);        // row (A) / col (B)
        int ko = (lane >> 4) * 8;             // k-octet start
        const short* base = (q < 2) ? Ahi : (q < 4) ? Alo : (q < 6) ? Bh : Bl;
        int rb = (q < 4) ? rowBase : colBase;
        gsrc[q] = base + (long)(rb + rc) * K + ko;
        ldst[q] = (void*)(smem + q * 4096 + wave * 1024);
    }

    float4v acc[4][4];
#pragma unroll
    for (int i = 0; i < 4; i++)
#pragma unroll
        for (int j = 0; j < 4; j++) acc[i][j] = (float4v){0.f, 0.f, 0.f, 0.f};

    for (int kt = 0; kt < K; kt += 32) {
#pragma unroll
        for (int q = 0; q < 8; q++) {
            async_cp16(gsrc[q], ldst[q]);
            gsrc[q] += 32;
        }
        __syncthreads();   // drains vmcnt(0): async loads landed; all waves synced

        short8 ah[4], al[4], bh[4], blv[4];
#pragma unroll
        for (int i = 0; i < 4; i++) {
            ah[i]  = AsHi[(wm * 4 + i) * 64 + lane];
            al[i]  = AsLo[(wm * 4 + i) * 64 + lane];
            bh[i]  = BsHi[(wn * 4 + i) * 64 + lane];
            blv[i] = BsLo[(wn * 4 + i) * 64 + lane];
        }
#pragma unroll
        for (int i = 0; i < 4; i++)
#pragma unroll
            for (int j = 0; j < 4; j++) {
                acc[i][j] = __builtin_amdgcn_mfma_f32_16x16x32_bf16(ah[i], bh[j],  acc[i][j], 0, 0, 0);
                acc[i][j] = __builtin_amdgcn_mfma_f32_16x16x32_bf16(ah[i], blv[j], acc[i][j], 0, 0, 0);
                acc[i][j] = __builtin_amdgcn_mfma_f32_16x16x32_bf16(al[i], bh[j],  acc[i][j], 0, 0, 0);
            }
        __syncthreads();   // protect LDS from next tile's async writes
    }

    // coalesced epilogue via LDS transpose (C/D layout: col=lane&15, row=(lane>>4)*4+reg)
    float* Ct = (float*)smem;
    int cq = lane >> 4, cn = lane & 15;
#pragma unroll
    for (int ph = 0; ph < 2; ph++) {
        if (wm == ph) {
#pragma unroll
            for (int i = 0; i < 4; i++)
#pragma unroll
                for (int j = 0; j < 4; j++) {
                    int lr = i * 16 + cq * 4;
                    int lc = wn * 64 + j * 16 + cn;
#pragma unroll
                    for (int r = 0; r < 4; r++)
                        Ct[(lr + r) * 132 + lc] = acc[i][j][r];
                }
        }
        __syncthreads();
#pragma unroll
        for (int k = 0; k < 4; k++) {
            int o = k * 256 + tid;
            int lr = o >> 4;
            int oc = (o & 15) << 3;
            int gr = rowBase + ph * 64 + lr;
            if (gr < M) {
                float4 f0 = *(float4*)&Ct[lr * 132 + oc];
                float4 f1 = *(float4*)&Ct[lr * 132 + oc + 4];
                int gc = colBase + oc;
                float4 b0 = *(const float4*)(bias + gc);
                float4 b1 = *(const float4*)(bias + gc + 4);
                __half2 p0 = __floats2half2_rn(f0.x + b0.x, f0.y + b0.y);
                __half2 p1 = __floats2half2_rn(f0.z + b0.z, f0.w + b0.w);
                __half2 p2 = __floats2half2_rn(f1.x + b1.x, f1.y + b1.y);
                __half2 p3 = __floats2half2_rn(f1.z + b1.z, f1.w + b1.w);
                uint4 ov;
                ov.x = *(unsigned int*)&p0;
                ov.y = *(unsigned int*)&p1;
                ov.z = *(unsigned int*)&p2;
                ov.w = *(unsigned int*)&p3;
                *(uint4*)(C + (size_t)gr * FDIM + gc) = ov;
            }
        }
        __syncthreads();
    }
}

// ---------------- per-node GATv2 aggregation, head-per-lane layout ----------------
// lane = slot*12 + head (60 active lanes): each lane owns one head's 32 channels of
// one edge -> the per-head logit dot is lane-local (no shfl tree in the edge loop),
// 5 edges in flight per pass (4 dwordx4 gathers/lane). Cross-slot reduce once per
// node via wave-local LDS (rotated 16B chunks: writes 8-way-free-ish, reads
// conflict-free). 4 independent waves (nodes) per 256-thread block, no barriers.

__global__ __launch_bounds__(256) void agg_kernel(const __half* __restrict__ xl,
                                                  const __half* __restrict__ xr,
                                                  const _Float16* __restrict__ att_h,
                                                  const float* __restrict__ bias,
                                                  const int* __restrict__ start,
                                                  const int* __restrict__ srcsOff,
                                                  short* __restrict__ houtHi,
                                                  short* __restrict__ houtLo,
                                                  const float* __restrict__ Wl,
                                                  const float* __restrict__ bl,
                                                  const float* __restrict__ Wr,
                                                  const float* __restrict__ br,
                                                  float* __restrict__ xloB,
                                                  float* __restrict__ xroB, int N) {
    __shared__ float lds[4][2048];   // per-wave 8KB scratch: 60x32 acc + s + inv_s
    int wave = threadIdx.x >> 6;
    int lane = threadIdx.x & 63;
    int node = blockIdx.x * 4 + wave;
    if (node >= N) return;           // no block-wide syncs anywhere: safe
    float* W = lds[wave];

    int h = lane % 12;                              // head owned by this lane
    int slot = (lane < 60) ? (lane / 12) : (1 << 28);   // idle lanes -> always masked

    long nodeOff = (long)node * (FDIM * 2);
    int hb = h << 6;                                // 64B = 32 halfs per head chunk

    // xr and att head chunks -> registers (16 hv2 each)
    hv2 xr2[16], at2[16];
    {
        const uint4* xrp = (const uint4*)((const char*)xr + nodeOff + hb);
        const uint4* atp = (const uint4*)((const char*)att_h + hb);
#pragma unroll
        for (int q = 0; q < 4; q++) {
            uint4 u = xrp[q];
            xr2[q * 4 + 0] = __builtin_bit_cast(hv2, u.x);
            xr2[q * 4 + 1] = __builtin_bit_cast(hv2, u.y);
            xr2[q * 4 + 2] = __builtin_bit_cast(hv2, u.z);
            xr2[q * 4 + 3] = __builtin_bit_cast(hv2, u.w);
            uint4 v = atp[q];
            at2[q * 4 + 0] = __builtin_bit_cast(hv2, v.x);
            at2[q * 4 + 1] = __builtin_bit_cast(hv2, v.y);
            at2[q * 4 + 2] = __builtin_bit_cast(hv2, v.z);
            at2[q * 4 + 3] = __builtin_bit_cast(hv2, v.w);
        }
    }
    const hv2 sl2 = {(_Float16)SLOPE, (_Float16)SLOPE};
    const char* xlb = (const char*)xl;

    int e0 = start[node], e1 = start[node + 1];

    float s = 0.f;
    f32x4 acc[8];
#pragma unroll
    for (int q = 0; q < 8; q++) acc[q] = (f32x4){0.f, 0.f, 0.f, 0.f};

    // edge index e0-1 encodes the self-loop; 5 edges per pass (one per slot)
    for (int base = e0 - 1; base < e1; base += 5) {
        int myIdx = base + slot;
        int ic = min(myIdx, e1 - 1);
        long off = (ic < e0) ? nodeOff : (long)srcsOff[ic];
        float mask = (myIdx < e1) ? 0.f : -1e30f;
        const uint4* p = (const uint4*)(xlb + off + hb);
        uint4 u0 = p[0], u1 = p[1], u2 = p[2], u3 = p[3];
        hv2 xa[16];
        xa[0]  = __builtin_bit_cast(hv2, u0.x); xa[1]  = __builtin_bit_cast(hv2, u0.y);
        xa[2]  = __builtin_bit_cast(hv2, u0.z); xa[3]  = __builtin_bit_cast(hv2, u0.w);
        xa[4]  = __builtin_bit_cast(hv2, u1.x); xa[5]  = __builtin_bit_cast(hv2, u1.y);
        xa[6]  = __builtin_bit_cast(hv2, u1.z); xa[7]  = __builtin_bit_cast(hv2, u1.w);
        xa[8]  = __builtin_bit_cast(hv2, u2.x); xa[9]  = __builtin_bit_cast(hv2, u2.y);
        xa[10] = __builtin_bit_cast(hv2, u2.z); xa[11] = __builtin_bit_cast(hv2, u2.w);
        xa[12] = __builtin_bit_cast(hv2, u3.x); xa[13] = __builtin_bit_cast(hv2, u3.y);
        xa[14] = __builtin_bit_cast(hv2, u3.z); xa[15] = __builtin_bit_cast(hv2, u3.w);

        float pc0 = 0.f, pc1 = 0.f;
#pragma unroll
        for (int k = 0; k < 16; k += 2) {
            hv2 t0 = xa[k] + xr2[k];
            hv2 t1 = xa[k + 1] + xr2[k + 1];
            t0 = __builtin_elementwise_max(t0, t0 * sl2);
            t1 = __builtin_elementwise_max(t1, t1 * sl2);
            pc0 = dot2acc(t0, at2[k], pc0);
            pc1 = dot2acc(t1, at2[k + 1], pc1);
        }
        float a = __expf(pc0 + pc1 + mask);
        s += a;
#pragma unroll
        for (int k = 0; k < 16; k++) {
            if (k & 1) {
                acc[k >> 1].z = fmaf(a, (float)xa[k].x, acc[k >> 1].z);
                acc[k >> 1].w = fmaf(a, (float)xa[k].y, acc[k >> 1].w);
            } else {
                acc[k >> 1].x = fmaf(a, (float)xa[k].x, acc[k >> 1].x);
                acc[k >> 1].y = fmaf(a, (float)xa[k].y, acc[k >> 1].y);
            }
        }
    }

    // ---- wave-local cross-slot reduction via LDS (no __syncthreads needed) ----
    if (lane < 60) {
#pragma unroll
        for (int q = 0; q < 8; q++)   // rotated 16B chunks: banks spread across lanes
            *(f32x4*)&W[lane * 32 + (((q + lane) & 7) << 2)] = acc[q];
        W[1920 + lane] = s;
    }
    asm volatile("s_waitcnt lgkmcnt(0)" ::: "memory");
    if (lane < 12) {
        float sv = W[1920 + lane] + W[1932 + lane] + W[1944 + lane] +
                   W[1956 + lane] + W[1968 + lane];
        W[1980 + lane] = 1.f / (sv + 1e-16f);
    }
    asm volatile("s_waitcnt lgkmcnt(0)" ::: "memory");

    // lane -> (channel c, head-group g): g=0 sums heads 0..5, g=1 heads 6..11
    int c = lane & 31;
    int g = lane >> 5;
    float o = 0.f;
#pragma unroll
    for (int hh = 0; hh < 6; hh++) {
        int hd = g * 6 + hh;
        float inv = W[1980 + hd];
        float t = 0.f;
#pragma unroll
        for (int s5 = 0; s5 < 5; s5++) {
            int r = hd + 12 * s5;
            t += W[r * 32 + ((((c >> 2) + r) & 7) << 2) + (c & 3)];
        }
        o = fmaf(inv, t, o);
    }
    o += __shfl_xor(o, 32);           // combine the two head-groups
    o = o * (1.f / 12.f) + bias[c];   // mean over 12 heads + bias
    o = o > 0.f ? o : expm1f(o);      // ELU

    if (houtHi) {
        unsigned int hbi = bf16_rne(o);
        unsigned int lbi = bf16_rne(o - __uint_as_float(hbi << 16));
        if (lane < 32) {
            houtHi[(size_t)node * 32 + c] = (short)hbi;
            houtLo[(size_t)node * 32 + c] = (short)lbi;
        }
    }
    if (Wl) {
        // output-layer projection: xlo/xro = o @ W[32x2] + b; reduce within lanes 0..31
        float2 wl = *(const float2*)(Wl + 2 * c);
        float2 wr = *(const float2*)(Wr + 2 * c);
        float l0 = o * wl.x, l1 = o * wl.y;
        float r0 = o * wr.x, r1 = o * wr.y;
#pragma unroll
        for (int st = 1; st <= 16; st <<= 1) {
            l0 += __shfl_xor(l0, st); l1 += __shfl_xor(l1, st);
            r0 += __shfl_xor(r0, st); r1 += __shfl_xor(r1, st);
        }
        if (lane == 0) {
            xloB[2 * node]     = l0 + bl[0];
            xloB[2 * node + 1] = l1 + bl[1];
            xroB[2 * node]     = r0 + br[0];
            xroB[2 * node + 1] = r1 + br[1];
        }
    }
}

// ---------------- output aggregation (heads=1, C=2): 8 lanes per node ----------------

__global__ __launch_bounds__(256) void out_agg_kernel(const float* __restrict__ xlo,
                                                      const float* __restrict__ xro,
                                                      const float* __restrict__ atto,
                                                      const float* __restrict__ biaso,
                                                      const int* __restrict__ start,
                                                      const int* __restrict__ srcs,
                                                      float* __restrict__ out, int N) {
    int g = (blockIdx.x * blockDim.x + threadIdx.x) >> 3;   // node
    int j = threadIdx.x & 7;
    if (g >= N) return;
    float a0 = atto[0], a1 = atto[1];
    float xr0 = xro[2 * g], xr1 = xro[2 * g + 1];
    float s = 0.f, acc0 = 0.f, acc1 = 0.f;
    int e0 = start[g], e1 = start[g + 1];
    for (int idx = e0 - 1 + j; idx < e1; idx += 8) {
        int jj = (idx < e0) ? g : srcs[idx];
        float x0 = xlo[2 * jj], x1 = xlo[2 * jj + 1];
        float t0 = x0 + xr0, t1 = x1 + xr1;
        t0 = fmaxf(t0, SLOPE * t0);
        t1 = fmaxf(t1, SLOPE * t1);
        float L = a0 * t0 + a1 * t1;
        float a = __expf(L);
        s += a;
        acc0 = fmaf(a, x0, acc0);
        acc1 = fmaf(a, x1, acc1);
    }
#pragma unroll
    for (int st = 1; st <= 4; st <<= 1) {
        s    += __shfl_xor(s, st);
        acc0 += __shfl_xor(acc0, st);
        acc1 += __shfl_xor(acc1, st);
    }
    if (j == 0) {
        float inv = 1.0f / (s + 1e-16f);
        out[2 * g]     = acc0 * inv + biaso[0];
        out[2 * g + 1] = acc1 * inv + biaso[1];
    }
}

// ---------------- launch ----------------

extern "C" void kernel_launch(void* const* d_in, const int* in_sizes, int n_in,
                              void* d_out, int out_size, void* d_ws, size_t ws_size,
                              hipStream_t stream) {
    const float* x    = (const float*)d_in[0];
    const int*   ei   = (const int*)d_in[1];
    const float* Wl0  = (const float*)d_in[2];
    const float* bl0  = (const float*)d_in[3];
    const float* Wr0  = (const float*)d_in[4];
    const float* br0  = (const float*)d_in[5];
    const float* att0 = (const float*)d_in[6];
    const float* bias0= (const float*)d_in[7];
    const float* Wl1  = (const float*)d_in[8];
    const float* bl1  = (const float*)d_in[9];
    const float* Wr1  = (const float*)d_in[10];
    const float* br1  = (const float*)d_in[11];
    const float* att1 = (const float*)d_in[12];
    const float* bias1= (const float*)d_in[13];
    const float* Wlo  = (const float*)d_in[14];
    const float* blo  = (const float*)d_in[15];
    const float* Wro  = (const float*)d_in[16];
    const float* bro  = (const float*)d_in[17];
    const float* atto = (const float*)d_in[18];
    const float* biaso= (const float*)d_in[19];

    const int N = in_sizes[0] / IN_DIM;
    const int E = in_sizes[1] / 2;

    char* ws = (char*)d_ws;
    size_t off = 0;
    auto take = [&](size_t bytes) -> char* {
        char* p = ws + off;
        off += (bytes + 255) & ~(size_t)255;
        return p;
    };
    __half* xlf = (__half*)take((size_t)N * FDIM * 2);
    __half* xrf = (__half*)take((size_t)N * FDIM * 2);
    float* xloB = (float*)take((size_t)N * 2 * 4);
    float* xroB = (float*)take((size_t)N * 2 * 4);
    int* cnt    = (int*)take((size_t)N * 4);
    int* startA = (int*)take((size_t)(N + 1) * 4);
    int* cursor = (int*)take((size_t)N * 4);
    int* srcs   = (int*)take((size_t)E * 4);
    int* srcsOff= (int*)take((size_t)E * 4);
    int  nb     = (N + 255) / 256;
    int* partials = (int*)take((size_t)nb * 4);
    short* Bl0h = (short*)take((size_t)FDIM * IN_DIM * 2);
    short* Bl0l = (short*)take((size_t)FDIM * IN_DIM * 2);
    short* Br0h = (short*)take((size_t)FDIM * IN_DIM * 2);
    short* Br0l = (short*)take((size_t)FDIM * IN_DIM * 2);
    short* Bl1h = (short*)take((size_t)FDIM * HID * 2);
    short* Bl1l = (short*)take((size_t)FDIM * HID * 2);
    short* Br1h = (short*)take((size_t)FDIM * HID * 2);
    short* Br1l = (short*)take((size_t)FDIM * HID * 2);
    short* xh   = (short*)take((size_t)N * IN_DIM * 2);
    short* xlo_ = (short*)take((size_t)N * IN_DIM * 2);
    short* h0h  = (short*)take((size_t)N * HID * 2);
    short* h0l  = (short*)take((size_t)N * HID * 2);
    _Float16* attH = (_Float16*)take((size_t)768 * 2);
    (void)take(32768);   // slack: OOB tile rows read valid ws memory

    const int* esrc = ei;
    const int* edst = ei + E;

    // merged prep (weights + att) + input bf16 split
    prep_all<<<(62208 + 255) / 256, 256, 0, stream>>>(Wl0, Wr0, Wl1, Wr1, att0, att1,
                                                      Bl0h, Bl0l, Br0h, Br0l,
                                                      Bl1h, Bl1l, Br1h, Br1l, attH);
    conv_x_kernel<<<((N * IN_DIM / 4) + 255) / 256, 256, 0, stream>>>(x, xh, xlo_, N * IN_DIM / 4);

    // CSR build (by destination)
    hipMemsetAsync(cnt, 0, (size_t)N * 4, stream);
    hist_kernel<<<(E + 255) / 256, 256, 0, stream>>>(edst, cnt, E);
    scan_partial_kernel<<<nb, 256, 0, stream>>>(cnt, partials, N);
    scan_top_kernel<<<1, 1024, 0, stream>>>(partials, nb);
    scan_final_kernel<<<nb, 256, 0, stream>>>(cnt, partials, startA, cursor, N);
    scatter_kernel<<<(E + 255) / 256, 256, 0, stream>>>(esrc, edst, cursor, srcs, srcsOff, E);

    dim3 ggrid((N + 127) / 128, 6);
    int aggGrid = (N + 3) / 4;
    // layer 0
    gemm_pair_async<<<ggrid, 256, 0, stream>>>(xh, xlo_, Bl0h, Bl0l, bl0, xlf, Br0h, Br0l, br0, xrf, N, IN_DIM);
    agg_kernel<<<aggGrid, 256, 0, stream>>>(xlf, xrf, attH, bias0, startA, srcsOff,
                                            h0h, h0l, nullptr, nullptr, nullptr, nullptr,
                                            nullptr, nullptr, N);
    // layer 1
    gemm_pair_async<<<ggrid, 256, 0, stream>>>(h0h, h0l, Bl1h, Bl1l, bl1, xlf, Br1h, Br1l, br1, xrf, N, HID);
    agg_kernel<<<aggGrid, 256, 0, stream>>>(xlf, xrf, attH + 384, bias1, startA, srcsOff,
                                            nullptr, nullptr, Wlo, blo, Wro, bro,
                                            xloB, xroB, N);
    // output aggregation (8 lanes/node)
    out_agg_kernel<<<((size_t)N * 8 + 255) / 256, 256, 0, stream>>>(xloB, xroB, atto, biaso, startA, srcs, (float*)d_out, N);
}